// Round 8
// baseline (105.877 us; speedup 1.0000x reference)
//
#include <hip/hip_runtime.h>
#include <hip/hip_bf16.h>

// B=128, V=1024, D=512. TWO kernels:
//  gemm_prep (480 blk x 256 thr):
//    [0,176)  three bf16 MFMA GEMMs, 64x64 tile, K=512 in 2 stages of 256
//             (all 32 global_load_dwordx4 of a stage in flight; stage-1 loads
//              issued before stage-0 MFMA -> ~2 latency exposures, not 8;
//              R5-vs-R7 fit: deep-prefetch gemm ~6us vs dbuf ~13us),
//             epilogue via LDS transpose -> all d_ws stores dwordx4 (R7: -7.6us):
//               fpT    = (feat @ Wf^T)^T   512x128 f32
//               ppbT   = Wp @ proto^T + b1 512x1024 bf16
//               dotraw = feat @ proto^T    128x1024 f32
//    [176,192) zipf ranks -> zw;  [192,480) row inv-norms
//  head (128 blk x 1024 thr): one block per row b; tid=(ks 16 x vt 64);
//    thread: 16 v (2x int4 ppbT loads), 32-deep k-seg; 64KB LDS partials
//    (summation order identical to R7 -> same absmax); in-block softmax -> out.
//    No wbuf, no 3rd kernel, no cross-block fences.

typedef __attribute__((ext_vector_type(8))) short bhalf8;
typedef __attribute__((ext_vector_type(4))) float f32x4;

static __device__ __forceinline__ unsigned short f2bf(float x) {
    union { __hip_bfloat16 h; unsigned short u; } cv;
    cv.h = __float2bfloat16(x);
    return cv.u;
}

static __device__ __forceinline__ int4 pack_bf16_8(float4 x, float4 y) {
    union { ushort u[8]; int4 v; } r;
    r.u[0] = f2bf(x.x); r.u[1] = f2bf(x.y); r.u[2] = f2bf(x.z); r.u[3] = f2bf(x.w);
    r.u[4] = f2bf(y.x); r.u[5] = f2bf(y.y); r.u[6] = f2bf(y.z); r.u[7] = f2bf(y.w);
    return r.v;
}

// ---------------- gemm_prep ----------------
__global__ __launch_bounds__(256) void gemm_prep_kernel(
    const float* __restrict__ feat, const float* __restrict__ counts,
    const float* __restrict__ proto, const float* __restrict__ zs,
    const float* __restrict__ W1, const float* __restrict__ b1,
    float* __restrict__ fpT, unsigned short* __restrict__ ppbT,
    float* __restrict__ dotraw,
    float* __restrict__ zw, float* __restrict__ invf, float* __restrict__ invp)
{
    int bx = blockIdx.x, tid = threadIdx.x;

    // 64 rows x 264 halfs (256 + 8 pad) per matrix = 67584 B total
    __shared__ unsigned short As[64 * 264];
    __shared__ unsigned short Bs[64 * 264];

    if (bx >= 176) {
        if (bx < 192) {
            // zipf: 64 i's per block; 4 threads per i scan quarters of j
            float* cn = (float*)&As[0];
            ((float4*)cn)[tid] = ((const float4*)counts)[tid];
            __syncthreads();
            int il = tid >> 2, q = tid & 3;
            int i = (bx - 176) * 64 + il;
            float ci = cn[i];
            int cnt = 0;
            int j0 = q * 256;
            #pragma unroll 8
            for (int j = j0; j < j0 + 256; ++j) {
                float cj = cn[j];
                cnt += (cj > ci) ? 1 : 0;
                cnt += (cj == ci && j < i) ? 1 : 0;  // stable tie-break
            }
            cnt += __shfl_xor(cnt, 1);
            cnt += __shfl_xor(cnt, 2);
            if (q == 0) zw[i] = powf((float)(cnt + 1), -zs[0]);
        } else {
            // inverse L2 norms: 4 rows/block, 1 wave/row (0..127 feat, 128..1151 proto)
            int nb = bx - 192;
            int w = tid >> 6, lane = tid & 63;
            int row = nb * 4 + w;
            const float* src = (row < 128) ? (feat + (size_t)row * 512)
                                           : (proto + (size_t)(row - 128) * 512);
            const float4* rp = (const float4*)src;
            float4 a = rp[lane * 2], b = rp[lane * 2 + 1];
            float ss = a.x*a.x + a.y*a.y + a.z*a.z + a.w*a.w
                     + b.x*b.x + b.y*b.y + b.z*b.z + b.w*b.w;
            for (int o = 32; o; o >>= 1) ss += __shfl_xor(ss, o);
            if (lane == 0) {
                float inv = 1.0f / fmaxf(sqrtf(ss), 1e-12f);
                if (row < 128) invf[row] = inv; else invp[row - 128] = inv;
            }
        }
        return;
    }

    // ---- GEMM: 64x64 tile, K=512 in 2 stages of 256 ----
    const float* A; const float* Bm;
    int lda, ldb, tm, tn, mode;  // 0: fpT (f32 transposed), 1: ppbT (bf16+bias), 2: dotraw
    if (bx < 16) {
        A = feat; lda = 512; Bm = W1; ldb = 1024; mode = 0;
        tm = bx >> 3; tn = bx & 7;
    } else if (bx < 144) {
        int t = bx - 16;
        A = W1 + 512; lda = 1024; Bm = proto; ldb = 512; mode = 1;
        tm = t >> 4; tn = t & 15;
    } else {
        int t = bx - 144;
        A = feat; lda = 512; Bm = proto; ldb = 512; mode = 2;
        tm = t >> 4; tn = t & 15;
    }

    int r = tid >> 2, q = tid & 3;           // row 0..63, quarter (64 floats)
    int wave = tid >> 6, lane = tid & 63;
    int fr = lane & 15, quad = lane >> 4;

    const float* Ag = A + (size_t)(tm * 64 + r) * lda + q * 64;
    const float* Bg = Bm + (size_t)(tn * 64 + r) * ldb + q * 64;
    int lbase = r * 264 + q * 64;            // halfs

    f32x4 acc0 = {0.f, 0.f, 0.f, 0.f};
    f32x4 acc1 = acc0, acc2 = acc0, acc3 = acc0;

    float4 La[16], Lb[16];

    // ---- stage 0: 32 dwordx4 in flight ----
    #pragma unroll
    for (int i = 0; i < 16; ++i) {
        La[i] = *(const float4*)(Ag + i * 4);
        Lb[i] = *(const float4*)(Bg + i * 4);
    }
    #pragma unroll
    for (int j = 0; j < 8; ++j) {
        *(int4*)&As[lbase + j * 8] = pack_bf16_8(La[2*j], La[2*j+1]);
        *(int4*)&Bs[lbase + j * 8] = pack_bf16_8(Lb[2*j], Lb[2*j+1]);
    }
    __syncthreads();

    // ---- stage 1 loads issued BEFORE stage-0 MFMA ----
    #pragma unroll
    for (int i = 0; i < 16; ++i) {
        La[i] = *(const float4*)(Ag + 256 + i * 4);
        Lb[i] = *(const float4*)(Bg + 256 + i * 4);
    }

    #pragma unroll
    for (int s = 0; s < 8; ++s) {
        int ko = s * 32 + quad * 8;
        bhalf8 af  = *(const bhalf8*)&As[(wave * 16 + fr) * 264 + ko];
        bhalf8 bf0 = *(const bhalf8*)&Bs[(fr) * 264 + ko];
        bhalf8 bf1 = *(const bhalf8*)&Bs[(16 + fr) * 264 + ko];
        bhalf8 bf2 = *(const bhalf8*)&Bs[(32 + fr) * 264 + ko];
        bhalf8 bf3 = *(const bhalf8*)&Bs[(48 + fr) * 264 + ko];
        acc0 = __builtin_amdgcn_mfma_f32_16x16x32_bf16(af, bf0, acc0, 0, 0, 0);
        acc1 = __builtin_amdgcn_mfma_f32_16x16x32_bf16(af, bf1, acc1, 0, 0, 0);
        acc2 = __builtin_amdgcn_mfma_f32_16x16x32_bf16(af, bf2, acc2, 0, 0, 0);
        acc3 = __builtin_amdgcn_mfma_f32_16x16x32_bf16(af, bf3, acc3, 0, 0, 0);
    }
    __syncthreads();

    #pragma unroll
    for (int j = 0; j < 8; ++j) {
        *(int4*)&As[lbase + j * 8] = pack_bf16_8(La[2*j], La[2*j+1]);
        *(int4*)&Bs[lbase + j * 8] = pack_bf16_8(Lb[2*j], Lb[2*j+1]);
    }
    __syncthreads();

    #pragma unroll
    for (int s = 0; s < 8; ++s) {
        int ko = s * 32 + quad * 8;
        bhalf8 af  = *(const bhalf8*)&As[(wave * 16 + fr) * 264 + ko];
        bhalf8 bf0 = *(const bhalf8*)&Bs[(fr) * 264 + ko];
        bhalf8 bf1 = *(const bhalf8*)&Bs[(16 + fr) * 264 + ko];
        bhalf8 bf2 = *(const bhalf8*)&Bs[(32 + fr) * 264 + ko];
        bhalf8 bf3 = *(const bhalf8*)&Bs[(48 + fr) * 264 + ko];
        acc0 = __builtin_amdgcn_mfma_f32_16x16x32_bf16(af, bf0, acc0, 0, 0, 0);
        acc1 = __builtin_amdgcn_mfma_f32_16x16x32_bf16(af, bf1, acc1, 0, 0, 0);
        acc2 = __builtin_amdgcn_mfma_f32_16x16x32_bf16(af, bf2, acc2, 0, 0, 0);
        acc3 = __builtin_amdgcn_mfma_f32_16x16x32_bf16(af, bf3, acc3, 0, 0, 0);
    }

    // ---- epilogue: C-tile -> LDS (64x65 f32) -> wide dwordx4 stores ----
    __syncthreads();
    float* Ct = (float*)&As[0];            // 64*65*4 = 16640 B <= 33792 B
    {
        // C/D layout: col = lane&15, row = quad*4 + reg  [m89/m91]
        int rl = wave * 16 + quad * 4;
        f32x4 accs[4] = {acc0, acc1, acc2, acc3};
        #pragma unroll
        for (int j = 0; j < 4; ++j)
            #pragma unroll
            for (int rr = 0; rr < 4; ++rr)
                Ct[(rl + rr) * 65 + fr + j * 16] = accs[j][rr];
    }
    __syncthreads();

    int tr = tid >> 2, tq = tid & 3;       // tr: tile row (m), tq: 16-col chunk
    if (mode == 0) {
        // fpT[k=n][b=m]: output row = n = tr, cols = m-range tq*16..+16
        float o[16];
        #pragma unroll
        for (int i = 0; i < 16; ++i) o[i] = Ct[(tq * 16 + i) * 65 + tr];
        float* dst = fpT + (size_t)(tn * 64 + tr) * 128 + tm * 64 + tq * 16;
        #pragma unroll
        for (int c = 0; c < 4; ++c) {
            float4 v = {o[c*4], o[c*4+1], o[c*4+2], o[c*4+3]};
            *(float4*)(dst + c * 4) = v;
        }
    } else if (mode == 1) {
        float bv = b1[tm * 64 + tr];
        float o[16];
        #pragma unroll
        for (int i = 0; i < 16; ++i) o[i] = Ct[tr * 65 + tq * 16 + i] + bv;
        unsigned short* dst = ppbT + (size_t)(tm * 64 + tr) * 1024 + tn * 64 + tq * 16;
        float4 x0 = {o[0], o[1], o[2], o[3]},   y0 = {o[4], o[5], o[6], o[7]};
        float4 x1 = {o[8], o[9], o[10], o[11]}, y1 = {o[12], o[13], o[14], o[15]};
        *(int4*)(dst)     = pack_bf16_8(x0, y0);
        *(int4*)(dst + 8) = pack_bf16_8(x1, y1);
    } else {
        float* dst = dotraw + (size_t)(tm * 64 + tr) * 1024 + tn * 64 + tq * 16;
        #pragma unroll
        for (int c = 0; c < 4; ++c) {
            float4 v = {Ct[tr * 65 + tq * 16 + c*4],     Ct[tr * 65 + tq * 16 + c*4 + 1],
                        Ct[tr * 65 + tq * 16 + c*4 + 2], Ct[tr * 65 + tq * 16 + c*4 + 3]};
            *(float4*)(dst + c * 4) = v;
        }
    }
}

// ---------------- head: hs + weights + softmax, one block per row b ----------------
// 128 blk x 1024 thr: tid = ks*64 + vt; ks in [0,16) 32-deep k-seg; vt in [0,64)
// -> 16 v's via 2 int4 loads/k. Summation order identical to R7 (abs identical).
__global__ __launch_bounds__(1024) void head_kernel(
    const float* __restrict__ fpT, const unsigned short* __restrict__ ppbT,
    const float* __restrict__ dotraw, const float* __restrict__ zw,
    const float* __restrict__ invf, const float* __restrict__ invp,
    const float* __restrict__ temp, const float* __restrict__ W2,
    const float* __restrict__ b2, float* __restrict__ out)
{
    int b = blockIdx.x, tid = threadIdx.x;
    int wave = tid >> 6, lane = tid & 63;
    int ks = tid >> 6, vt = tid & 63;      // one wave per ks
    int v16 = vt * 16, k0 = ks * 32;

    __shared__ float hpart[16 * 1024];     // 64 KB
    __shared__ float red[16];

    // zw-sum (all 1024 threads cover all 1024 v)
    float zwt = zw[tid];
    float zsl = zwt;
    for (int o = 32; o; o >>= 1) zsl += __shfl_xor(zsl, o);
    if (lane == 0) red[wave] = zsl;
    __syncthreads();
    float zsum = 0.f;
    #pragma unroll
    for (int i = 0; i < 16; ++i) zsum += red[i];
    float izw = 1.0f / fmaxf(zsum, 1e-8f);

    // hs partial: 32 k's x 16 v's (2 int4 = 16 bf16 per k)
    float h[16];
    #pragma unroll
    for (int i = 0; i < 16; ++i) h[i] = 0.f;
    const unsigned short* pc = ppbT + v16;
    #pragma unroll 8
    for (int k = k0; k < k0 + 32; ++k) {
        int4 pa = *(const int4*)(pc + ((size_t)k << 10));
        int4 pb = *(const int4*)(pc + ((size_t)k << 10) + 8);
        float f  = fpT[(size_t)k * 128 + b];   // uniform -> s_load
        float w2 = W2[k];                      // uniform -> s_load
        unsigned int u[8] = {(unsigned int)pa.x, (unsigned int)pa.y,
                             (unsigned int)pa.z, (unsigned int)pa.w,
                             (unsigned int)pb.x, (unsigned int)pb.y,
                             (unsigned int)pb.z, (unsigned int)pb.w};
        #pragma unroll
        for (int j = 0; j < 8; ++j) {
            float plo = __uint_as_float(u[j] << 16);
            float phi = __uint_as_float(u[j] & 0xffff0000u);
            h[2*j]   += fmaxf(f + plo, 0.f) * w2;
            h[2*j+1] += fmaxf(f + phi, 0.f) * w2;
        }
    }
    #pragma unroll
    for (int c = 0; c < 4; ++c) {
        float4 hv = {h[c*4], h[c*4+1], h[c*4+2], h[c*4+3]};
        *(float4*)&hpart[ks * 1024 + v16 + c * 4] = hv;
    }
    __syncthreads();

    // recombine (v = tid), weights
    int v = tid;
    float hh = 0.f;
    #pragma unroll
    for (int s = 0; s < 16; ++s) hh += hpart[s * 1024 + v];

    float it  = invf[b] / fmaxf(temp[0], 1e-4f);
    float sim = dotraw[(size_t)b * 1024 + v] * it * invp[v];
    float w = (zwt * izw) * (1.0f + sim) * (1.0f / (1.0f + expf(-(hh + b2[0]))));

    __syncthreads();   // red[] reuse

    // softmax over v
    float mx = w;
    for (int o = 32; o; o >>= 1) mx = fmaxf(mx, __shfl_xor(mx, o));
    if (lane == 0) red[wave] = mx;
    __syncthreads();
    mx = red[0];
    #pragma unroll
    for (int i = 1; i < 16; ++i) mx = fmaxf(mx, red[i]);
    __syncthreads();

    float e = expf(w - mx);
    float sm = e;
    for (int o = 32; o; o >>= 1) sm += __shfl_xor(sm, o);
    if (lane == 0) red[wave] = sm;
    __syncthreads();
    float tot = 0.f;
    #pragma unroll
    for (int i = 0; i < 16; ++i) tot += red[i];

    out[(size_t)b * 1024 + v] = e / tot;
}

// ---------------- launch ----------------
extern "C" void kernel_launch(void* const* d_in, const int* in_sizes, int n_in,
                              void* d_out, int out_size, void* d_ws, size_t ws_size,
                              hipStream_t stream) {
    const float* feat   = (const float*)d_in[0];
    const float* counts = (const float*)d_in[1];
    // d_in[2] total_count: ranks invariant under positive rescale -> unused
    const float* proto  = (const float*)d_in[3];
    const float* zs     = (const float*)d_in[4];
    const float* temp   = (const float*)d_in[5];
    const float* W1     = (const float*)d_in[6];
    const float* b1     = (const float*)d_in[7];
    const float* W2     = (const float*)d_in[8];
    const float* b2     = (const float*)d_in[9];

    char* ws = (char*)d_ws;
    float* zw     = (float*)(ws + 0);              // 1024 f32
    float* invf   = (float*)(ws + 4096);           // 128 f32
    float* invp   = (float*)(ws + 4608);           // 1024 f32
    float* fpT    = (float*)(ws + 8704);           // 512x128 f32 (transposed fp)
    float* dotraw = (float*)(ws + 270848);         // 128x1024 f32
    unsigned short* ppbT = (unsigned short*)(ws + 795136);  // 512x1024 bf16

    gemm_prep_kernel<<<480, 256, 0, stream>>>(feat, counts, proto, zs, W1, b1,
                                              fpT, ppbT, dotraw, zw, invf, invp);
    head_kernel<<<128, 1024, 0, stream>>>(fpT, ppbT, dotraw, zw, invf, invp,
                                          temp, W2, b2, (float*)d_out);
}